// Round 1
// 386.718 us; speedup vs baseline: 1.0347x; 1.0347x over previous
//
#include <hip/hip_runtime.h>

// Problem constants (match reference)
#define NROWS   262144
#define DIM     256
#define CLUSTER 512
#define NPAIR   (CLUSTER * (CLUSTER - 1) / 2)   // 130816
#define G       16                               // cluster groups (32 clusters each)
#define CPG     32                               // clusters per group
#define R       64                               // row chunks
#define CHUNK   (NROWS / R)                      // 4096 rows per chunk
#define CAP2    96                               // per-cluster list capacity (mean 8, +31 sigma)

// k_pairs tiling
#define T       16                               // clusters per tile
#define NT      (CLUSTER / T)                    // 32 tiles
#define TP      (NT * (NT + 1) / 2)              // 528 tile-pairs (incl. diagonal)

// ---------------- K1: per-cluster counting sort + register-accumulated sums -
// Block (g, r): scans labels[r*4096 .. +4096), builds a per-CLUSTER LDS list
// (32 lists). Wave w then processes its 8 clusters (cl = 4q+w) as contiguous
// segments: one float4 register accumulator per segment, no LDS RMW, no
// cross-iteration LDS dependency -> unroll-4 keeps 4 coalesced 1KB row loads
// in flight per wave (16 waves/CU = 64KB in flight, >> 9.2KB BW*latency).
// Matrix rows are read exactly once device-wide.
__global__ __launch_bounds__(256) void k_gather(const float* __restrict__ matrix,
                                                const int* __restrict__ label,
                                                float* __restrict__ partial,    // [CLUSTER][R][DIM]
                                                int* __restrict__ countpart) {  // [R][CLUSTER]
    int g = blockIdx.x & (G - 1);
    int r = blockIdx.x >> 4;           // 0..R-1
    int t = threadIdx.x;
    int w = t >> 6, lane = t & 63;
    int chunkStart = r * CHUNK;

    __shared__ unsigned short list[CPG][CAP2];     // 6 KB
    __shared__ int cnt[CPG];

    if (t < CPG) cnt[t] = 0;
    __syncthreads();

    // scan labels (int4-vectorized), build per-cluster lists
    const int4* lab4 = (const int4*)(label + chunkStart);
    for (int ii = t; ii < CHUNK / 4; ii += 256) {  // 4 iterations
        int4 L = lab4[ii];
        int base = ii << 2;
        int lab, cl, pos;
        lab = L.x; if ((lab >> 5) == g) { cl = lab & 31; pos = atomicAdd(&cnt[cl], 1); if (pos < CAP2) list[cl][pos] = (unsigned short)(base + 0); }
        lab = L.y; if ((lab >> 5) == g) { cl = lab & 31; pos = atomicAdd(&cnt[cl], 1); if (pos < CAP2) list[cl][pos] = (unsigned short)(base + 1); }
        lab = L.z; if ((lab >> 5) == g) { cl = lab & 31; pos = atomicAdd(&cnt[cl], 1); if (pos < CAP2) list[cl][pos] = (unsigned short)(base + 2); }
        lab = L.w; if ((lab >> 5) == g) { cl = lab & 31; pos = atomicAdd(&cnt[cl], 1); if (pos < CAP2) list[cl][pos] = (unsigned short)(base + 3); }
    }
    __syncthreads();

    if (t < CPG) countpart[r * CLUSTER + (g << 5) + t] = cnt[t];

    // wave w accumulates its 8 clusters; lane owns dims [4*lane, 4*lane+4)
    #pragma unroll
    for (int q = 0; q < 8; ++q) {
        int cl = (q << 2) | w;
        int m = min(cnt[cl], CAP2);
        float4 acc = make_float4(0.f, 0.f, 0.f, 0.f);
        #pragma unroll 4
        for (int k = 0; k < m; ++k) {
            int i = list[cl][k];
            float4 v = ((const float4*)(matrix + (size_t)(chunkStart + i) * DIM))[lane];
            acc.x += v.x; acc.y += v.y; acc.z += v.z; acc.w += v.w;
        }
        int c = (g << 5) | cl;
        ((float4*)(partial + ((size_t)c * R + r) * DIM))[lane] = acc;
    }
}

// ---------------- K2: reduce chunk partials -> centers ----------------------
// Wave 0 reduces the 64 per-chunk counts via shuffle (parallel, not a serial
// thread-0 loop); all 4 waves accumulate disjoint r-slices as float4, then a
// small LDS cross-wave reduce produces the center row.
__global__ __launch_bounds__(256) void k_center(const float* __restrict__ partial,
                                                const int* __restrict__ countpart,
                                                float* __restrict__ centers) {
    int c = blockIdx.x, t = threadIdx.x;
    int lane = t & 63, w = t >> 6;

    __shared__ float invc;
    __shared__ __align__(16) float4 red4[4][64];   // 4 KB

    if (w == 0) {
        int s = countpart[lane * CLUSTER + c];     // lane = chunk index r
        #pragma unroll
        for (int o = 32; o; o >>= 1) s += __shfl_xor(s, o, 64);
        if (lane == 0) invc = 1.0f / (float)max(s, 1);
    }

    const float4* p4 = (const float4*)(partial + (size_t)c * R * DIM);
    float4 acc = make_float4(0.f, 0.f, 0.f, 0.f);
    #pragma unroll
    for (int k = 0; k < 16; ++k) {                 // r = w*16 + k
        float4 v = p4[(size_t)(w * 16 + k) * 64 + lane];
        acc.x += v.x; acc.y += v.y; acc.z += v.z; acc.w += v.w;
    }
    red4[w][lane] = acc;
    __syncthreads();

    if (w == 0) {
        float4 s0 = red4[0][lane], s1 = red4[1][lane], s2 = red4[2][lane], s3 = red4[3][lane];
        float iv = invc;
        float4 o;
        o.x = (s0.x + s1.x + s2.x + s3.x) * iv;
        o.y = (s0.y + s1.y + s2.y + s3.y) * iv;
        o.z = (s0.z + s1.z + s2.z + s3.z) * iv;
        o.w = (s0.w + s1.w + s2.w + s3.w) * iv;
        ((float4*)(centers + (size_t)c * DIM))[lane] = o;
    }
}

// ---------------- K3: pairwise distances, 16x16 cluster tile per block ------
// Block = tile-pair (I<=J). Stages both 16x256 center tiles in LDS (+4-float
// row pad -> 4-bank rotation, <=2-way conflicts = free). Each thread owns one
// (i,j) pair completely: 64 float4 LDS iters, private accumulator, no serial
// cross-lane shuffle chain per pair. Diagonal tiles mask ti<tj (6% waste).
__global__ __launch_bounds__(256) void k_pairs(const float* __restrict__ centers,
                                               float* __restrict__ partials) {
    int bid = blockIdx.x;
    int I = 0, rem = bid;
    while (rem >= NT - I) { rem -= NT - I; ++I; }  // uniform, <=32 scalar iters
    int J = I + rem;

    __shared__ __align__(16) float cI[T][DIM + 4];
    __shared__ __align__(16) float cJ[T][DIM + 4];
    __shared__ float bsum[4];

    int t = threadIdx.x;
    int lane = t & 63, w = t >> 6;

    // stage tiles (coalesced float4 reads; centers are L2-resident)
    for (int idx = t; idx < T * 64; idx += 256) {  // 4 iterations, float4 units
        int rr = idx >> 6, d4 = idx & 63;
        float4 a = ((const float4*)(centers + (size_t)(I * T + rr) * DIM))[d4];
        *(float4*)&cI[rr][d4 * 4] = a;
        float4 b = ((const float4*)(centers + (size_t)(J * T + rr) * DIM))[d4];
        *(float4*)&cJ[rr][d4 * 4] = b;
    }
    __syncthreads();

    int ti = t >> 4, tj = t & 15;
    float acc = 0.f;
    #pragma unroll 8
    for (int d4 = 0; d4 < 64; ++d4) {
        float4 a = *(const float4*)&cI[ti][d4 * 4];
        float4 b = *(const float4*)&cJ[tj][d4 * 4];
        float dx = a.x - b.x, dy = a.y - b.y, dz = a.z - b.z, dw = a.w - b.w;
        acc += dx * dx + dy * dy + dz * dz + dw * dw;
    }
    bool valid = (I < J) || (ti < tj);
    float dist = valid ? sqrtf(fmaxf(acc, 1e-12f)) : 0.f;

    // block reduce: wave shuffle then 4-entry LDS
    #pragma unroll
    for (int o = 32; o; o >>= 1) dist += __shfl_xor(dist, o, 64);
    if (lane == 0) bsum[w] = dist;
    __syncthreads();
    if (t == 0) partials[bid] = bsum[0] + bsum[1] + bsum[2] + bsum[3];
}

// ---------------- K4: final reduce of block partials -> -mean ---------------
__global__ __launch_bounds__(256) void k_final(const float* __restrict__ partials, int nb,
                                               float* __restrict__ out) {
    __shared__ float s[256];
    float acc = 0.f;
    for (int i = threadIdx.x; i < nb; i += 256) acc += partials[i];
    s[threadIdx.x] = acc;
    __syncthreads();
    for (int d = 128; d; d >>= 1) {
        if (threadIdx.x < d) s[threadIdx.x] += s[threadIdx.x + d];
        __syncthreads();
    }
    if (threadIdx.x == 0) out[0] = -s[0] / (float)NPAIR;
}

extern "C" void kernel_launch(void* const* d_in, const int* in_sizes, int n_in,
                              void* d_out, int out_size, void* d_ws, size_t ws_size,
                              hipStream_t stream) {
    const float* matrix = (const float*)d_in[0];
    const int* label = (const int*)d_in[1];
    float* out = (float*)d_out;

    // workspace layout (all fully overwritten each call; ~33 MB)
    float* partial   = (float*)d_ws;                                  // 512*64*256 floats = 32 MB
    float* centers   = partial + (size_t)CLUSTER * R * DIM;           // 512*256 floats
    float* ppart     = centers + (size_t)CLUSTER * DIM;               // TP floats
    int*   countpart = (int*)(ppart + 4096);                          // 64*512 ints

    k_gather<<<G * R, 256, 0, stream>>>(matrix, label, partial, countpart);
    k_center<<<CLUSTER, 256, 0, stream>>>(partial, countpart, centers);
    k_pairs<<<TP, 256, 0, stream>>>(centers, ppart);
    k_final<<<1, 256, 0, stream>>>(ppart, TP, out);
}

// Round 2
// 386.135 us; speedup vs baseline: 1.0363x; 1.0015x over previous
//
#include <hip/hip_runtime.h>

// Problem constants (match reference)
#define NROWS   262144
#define DIM     256
#define CLUSTER 512
#define NPAIR   (CLUSTER * (CLUSTER - 1) / 2)   // 130816
#define G       16                               // cluster groups (32 clusters each)
#define CPG     32                               // clusters per group
#define R       32                               // row chunks
#define CHUNK   (NROWS / R)                      // 8192 rows per chunk
#define CAP2    96                               // per-cluster list capacity (mean 16, ~20 sigma)

// k_pairs tiling
#define T       16                               // clusters per tile
#define NT      (CLUSTER / T)                    // 32 tiles
#define TP      (NT * (NT + 1) / 2)              // 528 tile-pairs (incl. diagonal)

// ---------------- K1: per-cluster counting sort + register-accumulated sums -
// Block (g, r): scans labels[r*8192 .. +8192), builds per-cluster LDS lists.
// Wave w then accumulates its 8 clusters (cl = 4q+w) with a float4 register
// accumulator (no LDS RMW); unroll-4 keeps 4 coalesced 1KB row loads in
// flight per wave (8 waves/CU = 32KB in flight >> 9.2KB BW*latency product).
// Matrix rows are read exactly once device-wide; partial is 16MB (R=32).
// bid swizzle: all 16 group-blocks of one chunk land on the SAME XCD
// (bid % 8 = xcd fixed per chunk), so the 32KB label slice is fetched once
// per XCD L2 instead of 8x. Bijective: bid = (g<<5)|(r_sub<<3)|xcd.
__global__ __launch_bounds__(256) void k_gather(const float* __restrict__ matrix,
                                                const int* __restrict__ label,
                                                float* __restrict__ partial,    // [CLUSTER][R][DIM]
                                                int* __restrict__ countpart) {  // [R][CLUSTER]
    int bid = blockIdx.x;
    int g = bid >> 5;                              // 0..15
    int r = (bid & 7) | (((bid >> 3) & 3) << 3);   // xcd + 8*r_sub, 0..31
    int t = threadIdx.x;
    int w = t >> 6, lane = t & 63;
    int chunkStart = r * CHUNK;

    __shared__ unsigned short list[CPG][CAP2];     // 6 KB
    __shared__ int cnt[CPG];

    if (t < CPG) cnt[t] = 0;
    __syncthreads();

    // scan labels (int4-vectorized), build per-cluster lists
    const int4* lab4 = (const int4*)(label + chunkStart);
    for (int ii = t; ii < CHUNK / 4; ii += 256) {  // 8 iterations
        int4 L = lab4[ii];
        int base = ii << 2;
        int lab, cl, pos;
        lab = L.x; if ((lab >> 5) == g) { cl = lab & 31; pos = atomicAdd(&cnt[cl], 1); if (pos < CAP2) list[cl][pos] = (unsigned short)(base + 0); }
        lab = L.y; if ((lab >> 5) == g) { cl = lab & 31; pos = atomicAdd(&cnt[cl], 1); if (pos < CAP2) list[cl][pos] = (unsigned short)(base + 1); }
        lab = L.z; if ((lab >> 5) == g) { cl = lab & 31; pos = atomicAdd(&cnt[cl], 1); if (pos < CAP2) list[cl][pos] = (unsigned short)(base + 2); }
        lab = L.w; if ((lab >> 5) == g) { cl = lab & 31; pos = atomicAdd(&cnt[cl], 1); if (pos < CAP2) list[cl][pos] = (unsigned short)(base + 3); }
    }
    __syncthreads();

    if (t < CPG) countpart[r * CLUSTER + (g << 5) + t] = cnt[t];

    // wave w accumulates its 8 clusters; lane owns dims [4*lane, 4*lane+4)
    #pragma unroll
    for (int q = 0; q < 8; ++q) {
        int cl = (q << 2) | w;
        int m = min(cnt[cl], CAP2);
        float4 acc = make_float4(0.f, 0.f, 0.f, 0.f);
        #pragma unroll 4
        for (int k = 0; k < m; ++k) {
            int i = list[cl][k];
            float4 v = ((const float4*)(matrix + (size_t)(chunkStart + i) * DIM))[lane];
            acc.x += v.x; acc.y += v.y; acc.z += v.z; acc.w += v.w;
        }
        int c = (g << 5) | cl;
        ((float4*)(partial + ((size_t)c * R + r) * DIM))[lane] = acc;
    }
}

// ---------------- K2: reduce chunk partials -> centers ----------------------
// Wave 0 reduces the 32 per-chunk counts via shuffle; all 4 waves accumulate
// disjoint r-slices (8 each) as float4, then a small LDS cross-wave reduce.
__global__ __launch_bounds__(256) void k_center(const float* __restrict__ partial,
                                                const int* __restrict__ countpart,
                                                float* __restrict__ centers) {
    int c = blockIdx.x, t = threadIdx.x;
    int lane = t & 63, w = t >> 6;

    __shared__ float invc;
    __shared__ __align__(16) float4 red4[4][64];   // 4 KB

    if (w == 0) {
        int s = (lane < R) ? countpart[lane * CLUSTER + c] : 0;   // lane = chunk r
        #pragma unroll
        for (int o = 32; o; o >>= 1) s += __shfl_xor(s, o, 64);
        if (lane == 0) invc = 1.0f / (float)max(s, 1);
    }

    const float4* p4 = (const float4*)(partial + (size_t)c * R * DIM);
    float4 acc = make_float4(0.f, 0.f, 0.f, 0.f);
    #pragma unroll
    for (int k = 0; k < 8; ++k) {                  // r = w*8 + k
        float4 v = p4[(size_t)(w * 8 + k) * 64 + lane];
        acc.x += v.x; acc.y += v.y; acc.z += v.z; acc.w += v.w;
    }
    red4[w][lane] = acc;
    __syncthreads();

    if (w == 0) {
        float4 s0 = red4[0][lane], s1 = red4[1][lane], s2 = red4[2][lane], s3 = red4[3][lane];
        float iv = invc;
        float4 o;
        o.x = (s0.x + s1.x + s2.x + s3.x) * iv;
        o.y = (s0.y + s1.y + s2.y + s3.y) * iv;
        o.z = (s0.z + s1.z + s2.z + s3.z) * iv;
        o.w = (s0.w + s1.w + s2.w + s3.w) * iv;
        ((float4*)(centers + (size_t)c * DIM))[lane] = o;
    }
}

// ---------------- K3: pairwise distances, 16x16 cluster tile per block ------
// Block = tile-pair (I<=J). Stages both 16x256 center tiles in LDS (+4-float
// row pad -> 4-bank rotation, <=2-way conflicts = free). Each thread owns one
// (i,j) pair completely: 64 float4 LDS iters, private accumulator. Diagonal
// tiles mask ti<tj (6% waste). 528 blocks ~= 2/CU.
__global__ __launch_bounds__(256) void k_pairs(const float* __restrict__ centers,
                                               float* __restrict__ partials) {
    int bid = blockIdx.x;
    int I = 0, rem = bid;
    while (rem >= NT - I) { rem -= NT - I; ++I; }  // uniform, <=32 scalar iters
    int J = I + rem;

    __shared__ __align__(16) float cI[T][DIM + 4];
    __shared__ __align__(16) float cJ[T][DIM + 4];
    __shared__ float bsum[4];

    int t = threadIdx.x;
    int lane = t & 63, w = t >> 6;

    // stage tiles (coalesced float4 reads; centers are L2-resident)
    for (int idx = t; idx < T * 64; idx += 256) {  // 4 iterations, float4 units
        int rr = idx >> 6, d4 = idx & 63;
        float4 a = ((const float4*)(centers + (size_t)(I * T + rr) * DIM))[d4];
        *(float4*)&cI[rr][d4 * 4] = a;
        float4 b = ((const float4*)(centers + (size_t)(J * T + rr) * DIM))[d4];
        *(float4*)&cJ[rr][d4 * 4] = b;
    }
    __syncthreads();

    int ti = t >> 4, tj = t & 15;
    float acc = 0.f;
    #pragma unroll 8
    for (int d4 = 0; d4 < 64; ++d4) {
        float4 a = *(const float4*)&cI[ti][d4 * 4];
        float4 b = *(const float4*)&cJ[tj][d4 * 4];
        float dx = a.x - b.x, dy = a.y - b.y, dz = a.z - b.z, dw = a.w - b.w;
        acc += dx * dx + dy * dy + dz * dz + dw * dw;
    }
    bool valid = (I < J) || (ti < tj);
    float dist = valid ? sqrtf(fmaxf(acc, 1e-12f)) : 0.f;

    // block reduce: wave shuffle then 4-entry LDS
    #pragma unroll
    for (int o = 32; o; o >>= 1) dist += __shfl_xor(dist, o, 64);
    if (lane == 0) bsum[w] = dist;
    __syncthreads();
    if (t == 0) partials[bid] = bsum[0] + bsum[1] + bsum[2] + bsum[3];
}

// ---------------- K4: final reduce of block partials -> -mean ---------------
__global__ __launch_bounds__(256) void k_final(const float* __restrict__ partials, int nb,
                                               float* __restrict__ out) {
    __shared__ float s[256];
    float acc = 0.f;
    for (int i = threadIdx.x; i < nb; i += 256) acc += partials[i];
    s[threadIdx.x] = acc;
    __syncthreads();
    for (int d = 128; d; d >>= 1) {
        if (threadIdx.x < d) s[threadIdx.x] += s[threadIdx.x + d];
        __syncthreads();
    }
    if (threadIdx.x == 0) out[0] = -s[0] / (float)NPAIR;
}

extern "C" void kernel_launch(void* const* d_in, const int* in_sizes, int n_in,
                              void* d_out, int out_size, void* d_ws, size_t ws_size,
                              hipStream_t stream) {
    const float* matrix = (const float*)d_in[0];
    const int* label = (const int*)d_in[1];
    float* out = (float*)d_out;

    // workspace layout (all fully overwritten each call; ~17 MB)
    float* partial   = (float*)d_ws;                                  // 512*32*256 floats = 16 MB
    float* centers   = partial + (size_t)CLUSTER * R * DIM;           // 512*256 floats
    float* ppart     = centers + (size_t)CLUSTER * DIM;               // TP floats
    int*   countpart = (int*)(ppart + 1024);                          // 32*512 ints

    k_gather<<<G * R, 256, 0, stream>>>(matrix, label, partial, countpart);
    k_center<<<CLUSTER, 256, 0, stream>>>(partial, countpart, centers);
    k_pairs<<<TP, 256, 0, stream>>>(centers, ppart);
    k_final<<<1, 256, 0, stream>>>(ppart, TP, out);
}